// Round 11
// baseline (238.962 us; speedup 1.0000x reference)
//
#include <hip/hip_runtime.h>

#define NT 512
#define SCL (1.0f / 8192.0f)
#define PI_F 3.14159265358979323846f

// XOR swizzle: bijective involution on [0,8192); spreads the power-of-2 strided
// trip accesses across banks. Applied at EVERY cb access.
__device__ __forceinline__ int P(int i) { return i ^ ((i >> 5) & 31); }

__device__ __forceinline__ float2 cmul(float2 a, float2 b) {
  return make_float2(a.x * b.x - a.y * b.y, a.x * b.y + a.y * b.x);
}
__device__ __forceinline__ float2 csqr(float2 a) {
  return make_float2(a.x * a.x - a.y * a.y, 2.f * a.x * a.y);
}
__device__ __forceinline__ float2 cadd(float2 a, float2 b) { return make_float2(a.x + b.x, a.y + b.y); }
__device__ __forceinline__ float2 csub(float2 a, float2 b) { return make_float2(a.x - b.x, a.y - b.y); }
__device__ __forceinline__ float2 cmuli (float2 a) { return make_float2(-a.y,  a.x); } // *(+i)
__device__ __forceinline__ float2 cmulmi(float2 a) { return make_float2( a.y, -a.x); } // *(-i)

constexpr float RT2 = 0.70710678118654752440f;
constexpr float CQ1 = 0.92387953251128675613f; // cos(pi/8)
constexpr float SQ1 = 0.38268343236508977173f; // sin(pi/8)
// C8[k] = W8^k = e^{-i pi k/4}
constexpr float C8x[4] = {1.f,  RT2, 0.f, -RT2};
constexpr float C8y[4] = {0.f, -RT2, -1.f, -RT2};

// In-register 8-point DIF, stages at register strides 4,2,1.
// Stage stride s uses twiddle b^{4/s} * W_{2s}^{j mod s}; UNIT means b == 1.
template<bool UNIT>
__device__ __forceinline__ void r8_fwd(float2* e, float2 b) {
  float2 b2, b4;
  if (!UNIT) { b2 = csqr(b); b4 = csqr(b2); }
  #pragma unroll
  for (int j = 0; j < 4; ++j) {
    float2 u = e[j], v = e[j + 4];
    float2 d = csub(u, v);
    e[j] = cadd(u, v);
    float2 c8 = make_float2(C8x[j], C8y[j]);
    if (UNIT) e[j + 4] = (j == 0) ? d : cmul(d, c8);
    else      e[j + 4] = cmul(d, (j == 0) ? b : cmul(b, c8));
  }
  #pragma unroll
  for (int o = 0; o < 8; o += 4) {
    #pragma unroll
    for (int j = 0; j < 2; ++j) {
      float2 u = e[o + j], v = e[o + j + 2];
      float2 d = csub(u, v);
      e[o + j] = cadd(u, v);
      if (UNIT) e[o + j + 2] = (j == 0) ? d : cmulmi(d);
      else      e[o + j + 2] = cmul(d, (j == 0) ? b2 : cmulmi(b2));
    }
  }
  #pragma unroll
  for (int o = 0; o < 8; o += 2) {
    float2 u = e[o], v = e[o + 1];
    float2 d = csub(u, v);
    e[o] = cadd(u, v);
    e[o + 1] = UNIT ? d : cmul(d, b4);
  }
}

// In-register 8-point DIT inverse, stages at strides 1,2,4. g = conj(beta).
template<bool UNIT>
__device__ __forceinline__ void r8_inv(float2* e, float2 g) {
  float2 g2, g4;
  if (!UNIT) { g2 = csqr(g); g4 = csqr(g2); }
  #pragma unroll
  for (int o = 0; o < 8; o += 2) {
    float2 t = UNIT ? e[o + 1] : cmul(e[o + 1], g4);
    float2 u = e[o];
    e[o] = cadd(u, t); e[o + 1] = csub(u, t);
  }
  #pragma unroll
  for (int o = 0; o < 8; o += 4) {
    #pragma unroll
    for (int j = 0; j < 2; ++j) {
      float2 v = e[o + j + 2];
      float2 t;
      if (UNIT) t = (j == 0) ? v : cmuli(v);
      else      t = cmul(v, (j == 0) ? g2 : cmuli(g2));
      float2 u = e[o + j];
      e[o + j] = cadd(u, t); e[o + j + 2] = csub(u, t);
    }
  }
  #pragma unroll
  for (int j = 0; j < 4; ++j) {
    float2 v = e[j + 4];
    float2 t;
    float2 c8c = make_float2(C8x[j], -C8y[j]);
    if (UNIT) t = (j == 0) ? v : cmul(v, c8c);
    else      t = cmul(v, (j == 0) ? g : cmul(g, c8c));
    float2 u = e[j];
    e[j] = cadd(u, t); e[j + 4] = csub(u, t);
  }
}

// Each thread handles two radix-8 groups per trip: base and base+4096
// (same twiddle base for both, since the residue r is equal).
__device__ __forceinline__ void trip8_fwd(float2* cb, int base, int G, float2 b) {
  #pragma unroll 1
  for (int g = 0; g < 2; ++g) {
    int bs = base + g * 4096;
    float2 e[8];
    #pragma unroll
    for (int j = 0; j < 8; ++j) e[j] = cb[P(bs + G * j)];
    r8_fwd<false>(e, b);
    #pragma unroll
    for (int j = 0; j < 8; ++j) cb[P(bs + G * j)] = e[j];
  }
}

__device__ __forceinline__ void trip8_inv(float2* cb, int base, int G, float2 g) {
  #pragma unroll 1
  for (int gg = 0; gg < 2; ++gg) {
    int bs = base + gg * 4096;
    float2 e[8];
    #pragma unroll
    for (int j = 0; j < 8; ++j) e[j] = cb[P(bs + G * j)];
    r8_inv<false>(e, g);
    #pragma unroll
    for (int j = 0; j < 8; ++j) cb[P(bs + G * j)] = e[j];
  }
}

// K2a: forward FFT of the zero-padded filter (R7's verified radix-8 path).
// Writes T-hat*SCL to ThG in fftconv-MID consumption order:
// ThG[d*8192 + tid + 512*j + 4096*g]  (coalesced write here, coalesced read there).
__global__ __launch_bounds__(NT)
void that8(const float* __restrict__ tT, float2* __restrict__ ThG) {
  __shared__ float2 cb[8192];   // 64 KiB
  const int tid = threadIdx.x;
  const int d = blockIdx.x;

  const int baseA = tid;                            // G=512
  const int baseB = ((tid >> 6) << 9) + (tid & 63); // G=64
  const int baseC = ((tid >> 3) << 6) + (tid & 7);  // G=8
  const int baseM = tid << 3;                       // G=1

  float s0, c0; __sincosf(-PI_F * (float)tid / 2048.f, &s0, &c0);
  const float2 bA = make_float2(c0, s0);
  float s1, c1; __sincosf(-PI_F * (float)(tid & 63) / 256.f, &s1, &c1);
  const float2 bB = make_float2(c1, s1);
  float s2, c2; __sincosf(-PI_F * (float)(tid & 7) / 32.f, &s2, &c2);
  const float2 bC = make_float2(c2, s2);
  float sw, cw; __sincosf(-PI_F * (float)tid / 4096.f, &sw, &cw);
  const float2 W0 = make_float2(cw, sw);
  const float2 ROT = make_float2(CQ1, -SQ1);  // e^{-i pi/8}, step for n+=512

  {
    const float* tp = tT + (size_t)d * 4096;
    float2 w = W0;
    #pragma unroll
    for (int k = 0; k < 8; ++k) {
      int n = tid + NT * k;
      float tv = tp[n];
      cb[P(n)] = make_float2(tv, 0.f);
      cb[P(n + 4096)] = make_float2(tv * w.x, tv * w.y);
      w = cmul(w, ROT);
    }
  }
  __syncthreads();
  trip8_fwd(cb, baseA, 512, bA); __syncthreads();
  trip8_fwd(cb, baseB, 64,  bB); __syncthreads();
  trip8_fwd(cb, baseC, 8,   bC); __syncthreads();
  float2* thg = ThG + (size_t)d * 8192;
  #pragma unroll 1
  for (int g = 0; g < 2; ++g) {
    int bs = baseM + g * 4096;
    float2 e[8];
    #pragma unroll
    for (int j = 0; j < 8; ++j) e[j] = cb[P(bs + j)];
    r8_fwd<true>(e, make_float2(1.f, 0.f));
    #pragma unroll
    for (int j = 0; j < 8; ++j)
      thg[tid + 512 * j + 4096 * g] = make_float2(e[j].x * SCL, e[j].y * SCL);
  }
}

// K2b: per-channel FFT conv. R7's verified radix-8 structure with ONE change:
// T-hat comes from global (L2/L3-resident), not a second LDS buffer. cb-only
// LDS = 64 KiB -> 2 blocks/CU = 16 waves/CU = 4 waves/SIMD (vs R7's 2, R9's 1)
// at the NT=512 hard 128-VGPR cap, which radix-8 state fits.
// Stages: load-fused h=4096, A(G=512), B(G=64), C(G=8),
// MID(G=1: fwd 4,2,1 + That* + inv 1,2,4), C',B',A', store-fused h=4096.
__global__ __launch_bounds__(NT)
void fftconv(float* __restrict__ xT, const float2* __restrict__ ThG) {
  __shared__ float2 cb[8192];   // 64 KiB only
  const int tid = threadIdx.x;
  const int d = blockIdx.x;

  const int baseA = tid;
  const int baseB = ((tid >> 6) << 9) + (tid & 63);
  const int baseC = ((tid >> 3) << 6) + (tid & 7);
  const int baseM = tid << 3;

  float s0, c0; __sincosf(-PI_F * (float)tid / 2048.f, &s0, &c0);
  const float2 bA = make_float2(c0, s0);
  float s1, c1; __sincosf(-PI_F * (float)(tid & 63) / 256.f, &s1, &c1);
  const float2 bB = make_float2(c1, s1);
  float s2, c2; __sincosf(-PI_F * (float)(tid & 7) / 32.f, &s2, &c2);
  const float2 bC = make_float2(c2, s2);
  float sw, cw; __sincosf(-PI_F * (float)tid / 4096.f, &sw, &cw);
  const float2 W0 = make_float2(cw, sw);
  const float2 ROT  = make_float2(CQ1, -SQ1);
  const float2 ROTc = make_float2(CQ1,  SQ1);

  const float2* thg = ThG + (size_t)d * 8192;

  #pragma unroll 1
  for (int pass = 0; pass < 2; ++pass) {
    float* r0 = xT + ((size_t)(2 * pass)     * 1024 + d) * 4096;
    float* r1 = xT + ((size_t)(2 * pass + 1) * 1024 + d) * 4096;
    {
      float2 w = W0;
      #pragma unroll
      for (int k = 0; k < 8; ++k) {
        int n = tid + NT * k;
        float2 v = make_float2(r0[n], r1[n]);
        cb[P(n)] = v;
        cb[P(n + 4096)] = cmul(v, w);
        w = cmul(w, ROT);
      }
    }
    __syncthreads();
    trip8_fwd(cb, baseA, 512, bA); __syncthreads();
    trip8_fwd(cb, baseB, 64,  bB); __syncthreads();
    trip8_fwd(cb, baseC, 8,   bC); __syncthreads();
    { // MID group 0: T-hat loads (8x b64, coalesced) then compute
      float2 th[8];
      #pragma unroll
      for (int j = 0; j < 8; ++j) th[j] = thg[tid + 512 * j];
      float2 e[8];
      #pragma unroll
      for (int j = 0; j < 8; ++j) e[j] = cb[P(baseM + j)];
      r8_fwd<true>(e, make_float2(1.f, 0.f));
      #pragma unroll
      for (int j = 0; j < 8; ++j) e[j] = cmul(e[j], th[j]);
      r8_inv<true>(e, make_float2(1.f, 0.f));
      #pragma unroll
      for (int j = 0; j < 8; ++j) cb[P(baseM + j)] = e[j];
    }
    { // MID group 1
      float2 th[8];
      #pragma unroll
      for (int j = 0; j < 8; ++j) th[j] = thg[tid + 512 * j + 4096];
      float2 e[8];
      #pragma unroll
      for (int j = 0; j < 8; ++j) e[j] = cb[P(baseM + 4096 + j)];
      r8_fwd<true>(e, make_float2(1.f, 0.f));
      #pragma unroll
      for (int j = 0; j < 8; ++j) e[j] = cmul(e[j], th[j]);
      r8_inv<true>(e, make_float2(1.f, 0.f));
      #pragma unroll
      for (int j = 0; j < 8; ++j) cb[P(baseM + 4096 + j)] = e[j];
    }
    __syncthreads();
    trip8_inv(cb, baseC, 8,   make_float2(bC.x, -bC.y)); __syncthreads();
    trip8_inv(cb, baseB, 64,  make_float2(bB.x, -bB.y)); __syncthreads();
    trip8_inv(cb, baseA, 512, make_float2(bA.x, -bA.y)); __syncthreads();
    {
      float2 w = make_float2(cw, -sw);   // e^{+i pi tid/4096}
      #pragma unroll
      for (int k = 0; k < 8; ++k) {
        int n = tid + NT * k;
        float2 u = cb[P(n)];
        float2 v = cmul(cb[P(n + 4096)], w);
        r0[n] = u.x + v.x;
        r1[n] = u.y + v.y;
        w = cmul(w, ROTc);
      }
    }
    __syncthreads();
  }
}

// 64x64 tile transpose, 256 threads, float4 global I/O, padded LDS.
// At ~6.6 TB/s measured (R7) — HBM roofline; leave as is.
__global__ __launch_bounds__(256)
void transpose64(const float* __restrict__ src, float* __restrict__ dst, int R, int C) {
  __shared__ float tile[64][65];
  int t  = threadIdx.x;
  int c4 = t & 15;
  int r  = t >> 4;
  size_t slab = (size_t)blockIdx.z * (size_t)R * (size_t)C;
  const float* s = src + slab;
  float* dd = dst + slab;
  int col0 = blockIdx.x * 64, row0 = blockIdx.y * 64;
  #pragma unroll
  for (int k = 0; k < 4; ++k) {
    int rr = r + 16 * k;
    const float4 v = *(const float4*)(s + (size_t)(row0 + rr) * C + col0 + 4 * c4);
    tile[rr][4 * c4 + 0] = v.x;
    tile[rr][4 * c4 + 1] = v.y;
    tile[rr][4 * c4 + 2] = v.z;
    tile[rr][4 * c4 + 3] = v.w;
  }
  __syncthreads();
  #pragma unroll
  for (int k = 0; k < 4; ++k) {
    int cc = r + 16 * k;
    float4 w;
    w.x = tile[4 * c4 + 0][cc];
    w.y = tile[4 * c4 + 1][cc];
    w.z = tile[4 * c4 + 2][cc];
    w.w = tile[4 * c4 + 3][cc];
    *(float4*)(dd + (size_t)(col0 + cc) * R + row0 + 4 * c4) = w;
  }
}

extern "C" void kernel_launch(void* const* d_in, const int* in_sizes, int n_in,
                              void* d_out, int out_size, void* d_ws, size_t ws_size,
                              hipStream_t stream) {
  const float* x = (const float*)d_in[0];   // (4, 4096, 1024)
  const float* t = (const float*)d_in[1];   // (4096, 1024)
  float* out = (float*)d_out;               // (4, 4096, 1024) = 64 MB
  float* ws  = (float*)d_ws;
  float* xT  = ws;                                   // (4, 1024, 4096)  64 MB
  float* tT  = ws + (size_t)4 * 1024 * 4096;         // (1024, 4096)     16 MB
  // T-hat scratch lives in d_out (1024*8192 float2 = 64 MB exactly); consumed
  // by fftconv, then fully overwritten by the final transpose.
  float2* ThG = (float2*)d_out;

  transpose64<<<dim3(16, 64, 4), 256, 0, stream>>>(x, xT, 4096, 1024);
  transpose64<<<dim3(16, 64, 1), 256, 0, stream>>>(t, tT, 4096, 1024);

  that8<<<dim3(1024), NT, 0, stream>>>(tT, ThG);
  fftconv<<<dim3(1024), NT, 0, stream>>>(xT, ThG);

  transpose64<<<dim3(64, 16, 4), 256, 0, stream>>>(xT, out, 1024, 4096);
}

// Round 12
// 217.035 us; speedup vs baseline: 1.1010x; 1.1010x over previous
//
#include <hip/hip_runtime.h>

#define NT 256
#define SCL (1.0f / 8192.0f)
#define PI_F 3.14159265358979323846f

// XOR swizzle: bijective involution on [0,8192); spreads the power-of-2 strided
// trip accesses across banks (G=256: 2-way only; G=16: 2-way; G=1: 4-way).
__device__ __forceinline__ int P(int i) { return i ^ ((i >> 5) & 31); }

__device__ __forceinline__ float2 cmul(float2 a, float2 b) {
  return make_float2(a.x * b.x - a.y * b.y, a.x * b.y + a.y * b.x);
}
__device__ __forceinline__ float2 csqr(float2 a) {
  return make_float2(a.x * a.x - a.y * a.y, 2.f * a.x * a.y);
}
__device__ __forceinline__ float2 cadd(float2 a, float2 b) { return make_float2(a.x + b.x, a.y + b.y); }
__device__ __forceinline__ float2 csub(float2 a, float2 b) { return make_float2(a.x - b.x, a.y - b.y); }
__device__ __forceinline__ float2 cmuli (float2 a) { return make_float2(-a.y,  a.x); } // *(+i)
__device__ __forceinline__ float2 cmulmi(float2 a) { return make_float2( a.y, -a.x); } // *(-i)

constexpr float RT2 = 0.70710678118654752440f;
constexpr float CQ1 = 0.92387953251128675613f; // cos(pi/8)
constexpr float SQ1 = 0.38268343236508977173f; // sin(pi/8)
// C16[k] = W16^k = e^{-i pi k/8}
constexpr float C16x[8] = {1.f,  CQ1,  RT2,  SQ1, 0.f, -SQ1, -RT2, -CQ1};
constexpr float C16y[8] = {0.f, -SQ1, -RT2, -CQ1, -1.f, -CQ1, -RT2, -SQ1};
// C8[k] = W8^k = e^{-i pi k/4}
constexpr float C8x[4] = {1.f,  RT2, 0.f, -RT2};
constexpr float C8y[4] = {0.f, -RT2, -1.f, -RT2};
// C32[k] = W32^k = e^{-i pi k/16}
constexpr float C32x[16] = {1.f, 0.98078528040323044913f, 0.92387953251128675613f,
  0.83146961230254523708f, 0.70710678118654752440f, 0.55557023301960222474f,
  0.38268343236508977173f, 0.19509032201612826785f, 0.f, -0.19509032201612826785f,
  -0.38268343236508977173f, -0.55557023301960222474f, -0.70710678118654752440f,
  -0.83146961230254523708f, -0.92387953251128675613f, -0.98078528040323044913f};
constexpr float C32y[16] = {0.f, -0.19509032201612826785f, -0.38268343236508977173f,
  -0.55557023301960222474f, -0.70710678118654752440f, -0.83146961230254523708f,
  -0.92387953251128675613f, -0.98078528040323044913f, -1.f, -0.98078528040323044913f,
  -0.92387953251128675613f, -0.83146961230254523708f, -0.70710678118654752440f,
  -0.55557023301960222474f, -0.38268343236508977173f, -0.19509032201612826785f};

// In-register 16-point DIF, stages at register strides 8,4,2,1.
// Stage stride s uses twiddle b^{8/s} * W_{2s}^{j mod s}; UNIT means b == 1.
template<bool UNIT>
__device__ __forceinline__ void r16_fwd(float2* e, float2 b) {
  float2 b2, b4, b8, b4mi;
  if (!UNIT) { b2 = csqr(b); b4 = csqr(b2); b8 = csqr(b4); b4mi = cmulmi(b4); }
  #pragma unroll
  for (int j = 0; j < 8; ++j) {
    float2 u = e[j], v = e[j + 8];
    float2 d = csub(u, v);
    e[j] = cadd(u, v);
    if (UNIT) e[j + 8] = (j == 0) ? d : cmul(d, make_float2(C16x[j], C16y[j]));
    else {
      float2 tw = (j == 0) ? b : cmul(b, make_float2(C16x[j], C16y[j]));
      e[j + 8] = cmul(d, tw);
    }
  }
  #pragma unroll
  for (int o = 0; o < 16; o += 8) {
    #pragma unroll
    for (int j = 0; j < 4; ++j) {
      float2 u = e[o + j], v = e[o + j + 4];
      float2 d = csub(u, v);
      e[o + j] = cadd(u, v);
      if (UNIT) e[o + j + 4] = (j == 0) ? d : cmul(d, make_float2(C8x[j], C8y[j]));
      else {
        float2 tw = (j == 0) ? b2 : cmul(b2, make_float2(C8x[j], C8y[j]));
        e[o + j + 4] = cmul(d, tw);
      }
    }
  }
  #pragma unroll
  for (int o = 0; o < 16; o += 4) {
    #pragma unroll
    for (int j = 0; j < 2; ++j) {
      float2 u = e[o + j], v = e[o + j + 2];
      float2 d = csub(u, v);
      e[o + j] = cadd(u, v);
      if (UNIT) e[o + j + 2] = (j == 0) ? d : cmulmi(d);
      else      e[o + j + 2] = cmul(d, (j == 0) ? b4 : b4mi);
    }
  }
  #pragma unroll
  for (int o = 0; o < 16; o += 2) {
    float2 u = e[o], v = e[o + 1];
    float2 d = csub(u, v);
    e[o] = cadd(u, v);
    e[o + 1] = UNIT ? d : cmul(d, b8);
  }
}

// In-register 16-point DIT inverse, stages at register strides 1,2,4,8.
// Stage stride s uses twiddle g^{8/s} * conj(W_{2s})^{j mod s}; g = conj(beta).
template<bool UNIT>
__device__ __forceinline__ void r16_inv(float2* e, float2 g) {
  float2 g2, g4, g8, g4i;
  if (!UNIT) { g2 = csqr(g); g4 = csqr(g2); g8 = csqr(g4); g4i = cmuli(g4); }
  #pragma unroll
  for (int o = 0; o < 16; o += 2) {
    float2 t = UNIT ? e[o + 1] : cmul(e[o + 1], g8);
    float2 u = e[o];
    e[o] = cadd(u, t); e[o + 1] = csub(u, t);
  }
  #pragma unroll
  for (int o = 0; o < 16; o += 4) {
    #pragma unroll
    for (int j = 0; j < 2; ++j) {
      float2 v = e[o + j + 2];
      float2 t;
      if (UNIT) t = (j == 0) ? v : cmuli(v);
      else      t = cmul(v, (j == 0) ? g4 : g4i);
      float2 u = e[o + j];
      e[o + j] = cadd(u, t); e[o + j + 2] = csub(u, t);
    }
  }
  #pragma unroll
  for (int o = 0; o < 16; o += 8) {
    #pragma unroll
    for (int j = 0; j < 4; ++j) {
      float2 v = e[o + j + 4];
      float2 t;
      if (UNIT) t = (j == 0) ? v : cmul(v, make_float2(C8x[j], -C8y[j]));
      else      t = cmul(v, (j == 0) ? g2 : cmul(g2, make_float2(C8x[j], -C8y[j])));
      float2 u = e[o + j];
      e[o + j] = cadd(u, t); e[o + j + 4] = csub(u, t);
    }
  }
  #pragma unroll
  for (int j = 0; j < 8; ++j) {
    float2 v = e[j + 8];
    float2 t;
    if (UNIT) t = (j == 0) ? v : cmul(v, make_float2(C16x[j], -C16y[j]));
    else      t = cmul(v, (j == 0) ? g : cmul(g, make_float2(C16x[j], -C16y[j])));
    float2 u = e[j];
    e[j] = cadd(u, t); e[j + 8] = csub(u, t);
  }
}

// Radix-32 forward edge trip at G=256 (one group/thread, base = tid):
// covers strides 4096..256; the h=4096 stage is fused with the zero-padded
// upper half (E[n+4096] = x[n]*W_8192^n), so only 16 inputs are needed.
// After stage s=16, the two halves are independent radix-16 DIFs with base b^2.
// b = W_8192^tid. Writes all 32 results to cb.
__device__ __forceinline__ void trip32A_fwd(float2* cb, int tid, float2 b, const float2* x) {
  float2 e[32];
  #pragma unroll
  for (int j = 0; j < 16; ++j) {
    e[j] = x[j];
    float2 tw = (j == 0) ? b : cmul(b, make_float2(C32x[j], C32y[j]));
    e[j + 16] = cmul(x[j], tw);
  }
  float2 b2 = csqr(b);
  r16_fwd<false>(e, b2);
  r16_fwd<false>(e + 16, b2);
  #pragma unroll
  for (int j = 0; j < 32; ++j) cb[P(tid + 256 * j)] = e[j];
}

// Radix-32 inverse edge trip at G=256: two radix-16 DITs (base g^2), then the
// h=4096 stage fused into the global store — only outputs n<4096 are kept:
// y[n] = u + v * e^{+i pi n/4096}, n = tid + 256m, m=0..15. g = conj(W_8192^tid).
__device__ __forceinline__ void trip32E_inv(const float2* cb, int tid, float2 g,
                                            float* __restrict__ r0, float* __restrict__ r1) {
  float2 e[32];
  #pragma unroll
  for (int j = 0; j < 32; ++j) e[j] = cb[P(tid + 256 * j)];
  float2 g2 = csqr(g);
  r16_inv<false>(e, g2);
  r16_inv<false>(e + 16, g2);
  #pragma unroll
  for (int m = 0; m < 16; ++m) {
    float2 tw = (m == 0) ? g : cmul(g, make_float2(C32x[m], -C32y[m]));
    float2 t = cmul(e[m + 16], tw);
    int n = tid + 256 * m;
    r0[n] = e[m].x + t.x;
    r1[n] = e[m].y + t.y;
  }
}

// Middle radix-16 trips (verified R9 structure): two groups per thread
// (base and base+4096; same twiddle base since the residue r is equal).
__device__ __forceinline__ void trip_fwd2(float2* cb, int base, int G, float2 b) {
  #pragma unroll 1
  for (int g = 0; g < 2; ++g) {
    int bs = base + g * 4096;
    float2 e[16];
    #pragma unroll
    for (int j = 0; j < 16; ++j) e[j] = cb[P(bs + G * j)];
    r16_fwd<false>(e, b);
    #pragma unroll
    for (int j = 0; j < 16; ++j) cb[P(bs + G * j)] = e[j];
  }
}

__device__ __forceinline__ void trip_inv2(float2* cb, int base, int G, float2 g) {
  #pragma unroll 1
  for (int gg = 0; gg < 2; ++gg) {
    int bs = base + gg * 4096;
    float2 e[16];
    #pragma unroll
    for (int j = 0; j < 16; ++j) e[j] = cb[P(bs + G * j)];
    r16_inv<false>(e, g);
    #pragma unroll
    for (int j = 0; j < 16; ++j) cb[P(bs + G * j)] = e[j];
  }
}

// One pass (one complex pair of batch rows): 5 phases A,B,MID,D,E.
// x[16] holds the prefetched inputs (x.x = r0[n], x.y = r1[n], n = tid+256j).
__device__ __forceinline__ void pass_body(float2* cb, const float2* Th, int tid,
                                          int baseB, int baseM,
                                          float2 bA, float2 gA, float2 bB, float2 gB,
                                          const float2* x,
                                          float* __restrict__ r0, float* __restrict__ r1) {
  trip32A_fwd(cb, tid, bA, x);      __syncthreads();
  trip_fwd2(cb, baseB, 16, bB);     __syncthreads();
  #pragma unroll 1
  for (int g = 0; g < 2; ++g) {
    int bs = baseM + g * 4096;
    float2 e[16];
    #pragma unroll
    for (int j = 0; j < 16; ++j) e[j] = cb[P(bs + j)];
    r16_fwd<true>(e, make_float2(1.f, 0.f));
    #pragma unroll
    for (int j = 0; j < 16; ++j) e[j] = cmul(e[j], Th[P(bs + j)]);
    r16_inv<true>(e, make_float2(1.f, 0.f));
    #pragma unroll
    for (int j = 0; j < 16; ++j) cb[P(bs + j)] = e[j];
  }
  __syncthreads();
  trip_inv2(cb, baseB, 16, gB);     __syncthreads();
  trip32E_inv(cb, tid, gA, r0, r1); __syncthreads();
}

// One workgroup per channel d. xT: (b, d, n) rows of 4096; tT: (d, n).
// 8192-pt FFT conv. 13 stages = 5 (radix-32 edge, global-I/O-fused) + 4 + 4.
// Phases per pass: A,B,MID,D,E = 5 (R9 had 7 + standalone load/store phases).
// All global reads (t row, pass0 x, pass1 x) are register-prefetched at kernel
// start, 3-8 phases before first use -> HBM latency hidden under compute.
// NT=256 -> 256-VGPR cap; live set ~180 (e[32]=64 + xB=32 + misc) -> no spill.
// LDS = cb + Th = 128 KiB -> 1 WG/CU (R9's proven-clean occupancy geometry).
__global__ __launch_bounds__(NT)
void fftconv(float* __restrict__ xT, const float* __restrict__ tT) {
  __shared__ float2 cb[8192];   // 64 KiB working buffer
  __shared__ float2 Th[8192];   // 64 KiB T-hat (scaled), written once, read 2x
  const int tid = threadIdx.x;
  const int d = blockIdx.x;

  const int baseB = (tid >> 4) * 256 + (tid & 15); // trips B/D: G=16
  const int baseM = tid * 16;                      // MID: G=1

  float sw, cw; __sincosf(-PI_F * (float)tid / 4096.f, &sw, &cw);
  const float2 bA = make_float2(cw, sw);    // W_8192^tid (radix-32 base)
  const float2 gA = make_float2(cw, -sw);
  float sb, cbv; __sincosf(-PI_F * (float)(tid & 15) / 128.f, &sb, &cbv);
  const float2 bB = make_float2(cbv, sb);   // W_256^(tid&15)
  const float2 gB = make_float2(cbv, -sb);

  // ---- prefetch ALL global inputs into registers up front ----
  const float* tp = tT + (size_t)d * 4096;
  float2 tx[16];
  #pragma unroll
  for (int j = 0; j < 16; ++j) tx[j] = make_float2(tp[tid + 256 * j], 0.f);

  float* r0a = xT + ((size_t)0 * 1024 + d) * 4096;
  float* r1a = xT + ((size_t)1 * 1024 + d) * 4096;
  float2 xA[16];
  #pragma unroll
  for (int j = 0; j < 16; ++j) {
    int n = tid + 256 * j;
    xA[j] = make_float2(r0a[n], r1a[n]);
  }
  float* r0b = xT + ((size_t)2 * 1024 + d) * 4096;
  float* r1b = xT + ((size_t)3 * 1024 + d) * 4096;
  float2 xB[16];
  #pragma unroll
  for (int j = 0; j < 16; ++j) {
    int n = tid + 256 * j;
    xB[j] = make_float2(r0b[n], r1b[n]);
  }

  // ---- T-hat: A(radix-32, pad-fused) -> B -> MID-fwd -> Th (scaled), 3 phases ----
  trip32A_fwd(cb, tid, bA, tx);  __syncthreads();
  trip_fwd2(cb, baseB, 16, bB);  __syncthreads();
  #pragma unroll 1
  for (int g = 0; g < 2; ++g) {
    int bs = baseM + g * 4096;
    float2 e[16];
    #pragma unroll
    for (int j = 0; j < 16; ++j) e[j] = cb[P(bs + j)];
    r16_fwd<true>(e, make_float2(1.f, 0.f));
    #pragma unroll
    for (int j = 0; j < 16; ++j) Th[P(bs + j)] = make_float2(e[j].x * SCL, e[j].y * SCL);
  }
  __syncthreads();

  // ---- two complex passes; real filter => two outputs per pass directly ----
  pass_body(cb, Th, tid, baseB, baseM, bA, gA, bB, gB, xA, r0a, r1a);
  pass_body(cb, Th, tid, baseB, baseM, bA, gA, bB, gB, xB, r0b, r1b);
}

// 64x64 tile transpose, 256 threads, float4 global I/O, padded LDS.
// At ~6.6 TB/s measured (R7) — HBM roofline; leave as is.
__global__ __launch_bounds__(256)
void transpose64(const float* __restrict__ src, float* __restrict__ dst, int R, int C) {
  __shared__ float tile[64][65];
  int t  = threadIdx.x;
  int c4 = t & 15;
  int r  = t >> 4;
  size_t slab = (size_t)blockIdx.z * (size_t)R * (size_t)C;
  const float* s = src + slab;
  float* dd = dst + slab;
  int col0 = blockIdx.x * 64, row0 = blockIdx.y * 64;
  #pragma unroll
  for (int k = 0; k < 4; ++k) {
    int rr = r + 16 * k;
    const float4 v = *(const float4*)(s + (size_t)(row0 + rr) * C + col0 + 4 * c4);
    tile[rr][4 * c4 + 0] = v.x;
    tile[rr][4 * c4 + 1] = v.y;
    tile[rr][4 * c4 + 2] = v.z;
    tile[rr][4 * c4 + 3] = v.w;
  }
  __syncthreads();
  #pragma unroll
  for (int k = 0; k < 4; ++k) {
    int cc = r + 16 * k;
    float4 w;
    w.x = tile[4 * c4 + 0][cc];
    w.y = tile[4 * c4 + 1][cc];
    w.z = tile[4 * c4 + 2][cc];
    w.w = tile[4 * c4 + 3][cc];
    *(float4*)(dd + (size_t)(col0 + cc) * R + row0 + 4 * c4) = w;
  }
}

extern "C" void kernel_launch(void* const* d_in, const int* in_sizes, int n_in,
                              void* d_out, int out_size, void* d_ws, size_t ws_size,
                              hipStream_t stream) {
  const float* x = (const float*)d_in[0];   // (4, 4096, 1024)
  const float* t = (const float*)d_in[1];   // (4096, 1024)
  float* out = (float*)d_out;               // (4, 4096, 1024)
  float* ws  = (float*)d_ws;
  float* xT  = ws;                                   // (4, 1024, 4096)  64 MB
  float* tT  = ws + (size_t)4 * 1024 * 4096;         // (1024, 4096)     16 MB

  transpose64<<<dim3(16, 64, 4), 256, 0, stream>>>(x, xT, 4096, 1024);
  transpose64<<<dim3(16, 64, 1), 256, 0, stream>>>(t, tT, 4096, 1024);

  fftconv<<<dim3(1024), NT, 0, stream>>>(xT, tT);

  transpose64<<<dim3(64, 16, 4), 256, 0, stream>>>(xT, out, 1024, 4096);
}

// Round 13
// 175.068 us; speedup vs baseline: 1.3650x; 1.2397x over previous
//
#include <hip/hip_runtime.h>

#define NT 256
#define SCL (1.0f / 8192.0f)
#define PI_F 3.14159265358979323846f

// XOR swizzle: bijective involution on [0,4096); spreads power-of-2 strided
// trip accesses across banks. Applied at EVERY cb access.
__device__ __forceinline__ int P(int i) { return i ^ ((i >> 5) & 31); }

__device__ __forceinline__ float2 cmul(float2 a, float2 b) {
  return make_float2(a.x * b.x - a.y * b.y, a.x * b.y + a.y * b.x);
}
__device__ __forceinline__ float2 csqr(float2 a) {
  return make_float2(a.x * a.x - a.y * a.y, 2.f * a.x * a.y);
}
__device__ __forceinline__ float2 cadd(float2 a, float2 b) { return make_float2(a.x + b.x, a.y + b.y); }
__device__ __forceinline__ float2 csub(float2 a, float2 b) { return make_float2(a.x - b.x, a.y - b.y); }
__device__ __forceinline__ float2 cmuli (float2 a) { return make_float2(-a.y,  a.x); } // *(+i)
__device__ __forceinline__ float2 cmulmi(float2 a) { return make_float2( a.y, -a.x); } // *(-i)

constexpr float RT2 = 0.70710678118654752440f;
constexpr float CQ1 = 0.92387953251128675613f; // cos(pi/8)
constexpr float SQ1 = 0.38268343236508977173f; // sin(pi/8)
// C16[k] = W16^k = e^{-i pi k/8}
constexpr float C16x[8] = {1.f,  CQ1,  RT2,  SQ1, 0.f, -SQ1, -RT2, -CQ1};
constexpr float C16y[8] = {0.f, -SQ1, -RT2, -CQ1, -1.f, -CQ1, -RT2, -SQ1};
// C8[k] = W8^k = e^{-i pi k/4}
constexpr float C8x[4] = {1.f,  RT2, 0.f, -RT2};
constexpr float C8y[4] = {0.f, -RT2, -1.f, -RT2};
// C32[k] = W32^k = e^{-i pi k/16}
constexpr float C32x[16] = {1.f, 0.98078528040323044913f, 0.92387953251128675613f,
  0.83146961230254523708f, 0.70710678118654752440f, 0.55557023301960222474f,
  0.38268343236508977173f, 0.19509032201612826785f, 0.f, -0.19509032201612826785f,
  -0.38268343236508977173f, -0.55557023301960222474f, -0.70710678118654752440f,
  -0.83146961230254523708f, -0.92387953251128675613f, -0.98078528040323044913f};
constexpr float C32y[16] = {0.f, -0.19509032201612826785f, -0.38268343236508977173f,
  -0.55557023301960222474f, -0.70710678118654752440f, -0.83146961230254523708f,
  -0.92387953251128675613f, -0.98078528040323044913f, -1.f, -0.98078528040323044913f,
  -0.92387953251128675613f, -0.83146961230254523708f, -0.70710678118654752440f,
  -0.55557023301960222474f, -0.38268343236508977173f, -0.19509032201612826785f};

// In-register 16-point DIF, stages at register strides 8,4,2,1.
// Stage stride s uses twiddle b^{8/s} * W_{2s}^{j mod s}; UNIT means b == 1.
template<bool UNIT>
__device__ __forceinline__ void r16_fwd(float2* e, float2 b) {
  float2 b2, b4, b8, b4mi;
  if (!UNIT) { b2 = csqr(b); b4 = csqr(b2); b8 = csqr(b4); b4mi = cmulmi(b4); }
  #pragma unroll
  for (int j = 0; j < 8; ++j) {
    float2 u = e[j], v = e[j + 8];
    float2 d = csub(u, v);
    e[j] = cadd(u, v);
    if (UNIT) e[j + 8] = (j == 0) ? d : cmul(d, make_float2(C16x[j], C16y[j]));
    else {
      float2 tw = (j == 0) ? b : cmul(b, make_float2(C16x[j], C16y[j]));
      e[j + 8] = cmul(d, tw);
    }
  }
  #pragma unroll
  for (int o = 0; o < 16; o += 8) {
    #pragma unroll
    for (int j = 0; j < 4; ++j) {
      float2 u = e[o + j], v = e[o + j + 4];
      float2 d = csub(u, v);
      e[o + j] = cadd(u, v);
      if (UNIT) e[o + j + 4] = (j == 0) ? d : cmul(d, make_float2(C8x[j], C8y[j]));
      else {
        float2 tw = (j == 0) ? b2 : cmul(b2, make_float2(C8x[j], C8y[j]));
        e[o + j + 4] = cmul(d, tw);
      }
    }
  }
  #pragma unroll
  for (int o = 0; o < 16; o += 4) {
    #pragma unroll
    for (int j = 0; j < 2; ++j) {
      float2 u = e[o + j], v = e[o + j + 2];
      float2 d = csub(u, v);
      e[o + j] = cadd(u, v);
      if (UNIT) e[o + j + 2] = (j == 0) ? d : cmulmi(d);
      else      e[o + j + 2] = cmul(d, (j == 0) ? b4 : b4mi);
    }
  }
  #pragma unroll
  for (int o = 0; o < 16; o += 2) {
    float2 u = e[o], v = e[o + 1];
    float2 d = csub(u, v);
    e[o] = cadd(u, v);
    e[o + 1] = UNIT ? d : cmul(d, b8);
  }
}

// In-register 16-point DIT inverse, stages at register strides 1,2,4,8.
// Stage stride s uses twiddle g^{8/s} * conj(W_{2s})^{j mod s}; g = conj(beta).
template<bool UNIT>
__device__ __forceinline__ void r16_inv(float2* e, float2 g) {
  float2 g2, g4, g8, g4i;
  if (!UNIT) { g2 = csqr(g); g4 = csqr(g2); g8 = csqr(g4); g4i = cmuli(g4); }
  #pragma unroll
  for (int o = 0; o < 16; o += 2) {
    float2 t = UNIT ? e[o + 1] : cmul(e[o + 1], g8);
    float2 u = e[o];
    e[o] = cadd(u, t); e[o + 1] = csub(u, t);
  }
  #pragma unroll
  for (int o = 0; o < 16; o += 4) {
    #pragma unroll
    for (int j = 0; j < 2; ++j) {
      float2 v = e[o + j + 2];
      float2 t;
      if (UNIT) t = (j == 0) ? v : cmuli(v);
      else      t = cmul(v, (j == 0) ? g4 : g4i);
      float2 u = e[o + j];
      e[o + j] = cadd(u, t); e[o + j + 2] = csub(u, t);
    }
  }
  #pragma unroll
  for (int o = 0; o < 16; o += 8) {
    #pragma unroll
    for (int j = 0; j < 4; ++j) {
      float2 v = e[o + j + 4];
      float2 t;
      if (UNIT) t = (j == 0) ? v : cmul(v, make_float2(C8x[j], -C8y[j]));
      else      t = cmul(v, (j == 0) ? g2 : cmul(g2, make_float2(C8x[j], -C8y[j])));
      float2 u = e[o + j];
      e[o + j] = cadd(u, t); e[o + j + 4] = csub(u, t);
    }
  }
  #pragma unroll
  for (int j = 0; j < 8; ++j) {
    float2 v = e[j + 8];
    float2 t;
    if (UNIT) t = (j == 0) ? v : cmul(v, make_float2(C16x[j], -C16y[j]));
    else      t = cmul(v, (j == 0) ? g : cmul(g, make_float2(C16x[j], -C16y[j])));
    float2 u = e[j];
    e[j] = cadd(u, t); e[j + 8] = csub(u, t);
  }
}

// Single-group radix-16 trips on the 4096-entry buffer (one group per thread).
__device__ __forceinline__ void tripf(float2* cb, int base, int G, float2 b) {
  float2 e[16];
  #pragma unroll
  for (int j = 0; j < 16; ++j) e[j] = cb[P(base + G * j)];
  r16_fwd<false>(e, b);
  #pragma unroll
  for (int j = 0; j < 16; ++j) cb[P(base + G * j)] = e[j];
}

__device__ __forceinline__ void tripi(float2* cb, int base, int G, float2 g) {
  float2 e[16];
  #pragma unroll
  for (int j = 0; j < 16; ++j) e[j] = cb[P(base + G * j)];
  r16_inv<false>(e, g);
  #pragma unroll
  for (int j = 0; j < 16; ++j) cb[P(base + G * j)] = e[j];
}

// K2a: T-hat halves. The h=4096 DIF stage of the 8192-pt transform splits it
// into two independent 4096-pt FFTs: half0 input = t[n], half1 = t[n]*W_8192^n.
// 4096 = 16^3: trips A(G=256), B(G=16), MID-fwd(G=1). Output (scaled 1/8192)
// written consumption-ordered: ThG[(2d+half)*4096 + tid + 256*j] (coalesced
// write here, coalesced read in fftconv; both sides use the same (tid,j) map).
__global__ __launch_bounds__(NT)
void that4k(const float* __restrict__ tT, float2* __restrict__ ThG) {
  __shared__ float2 cb[4096];   // 32 KiB
  const int tid = threadIdx.x;
  const int d = blockIdx.x;
  const int half = blockIdx.y;

  const int baseB = (tid >> 4) * 256 + (tid & 15);

  float sa, ca; __sincosf(-PI_F * (float)tid / 2048.f, &sa, &ca);
  const float2 bA = make_float2(ca, sa);        // W_4096^tid
  float sb, cv; __sincosf(-PI_F * (float)(tid & 15) / 128.f, &sb, &cv);
  const float2 bB = make_float2(cv, sb);        // W_256^(tid&15)
  float sw, cw; __sincosf(-PI_F * (float)tid / 4096.f, &sw, &cw);
  const float2 whi = make_float2(cw, sw);       // W_8192^tid

  const float* tp = tT + (size_t)d * 4096;
  #pragma unroll
  for (int j = 0; j < 16; ++j) {
    int n = tid + 256 * j;
    float tv = tp[n];
    float2 v;
    if (half == 0) v = make_float2(tv, 0.f);
    else {
      float2 w = cmul(whi, make_float2(C32x[j], C32y[j]));  // W_8192^n
      v = make_float2(tv * w.x, tv * w.y);
    }
    cb[P(n)] = v;
  }
  __syncthreads();
  tripf(cb, tid, 256, bA);  __syncthreads();
  tripf(cb, baseB, 16, bB); __syncthreads();
  float2* thg = ThG + ((size_t)d * 2 + half) * 4096;
  float2 e[16];
  #pragma unroll
  for (int j = 0; j < 16; ++j) e[j] = cb[P(tid * 16 + j)];
  r16_fwd<true>(e, make_float2(1.f, 0.f));
  #pragma unroll
  for (int j = 0; j < 16; ++j)
    thg[tid + 256 * j] = make_float2(e[j].x * SCL, e[j].y * SCL);
}

// K2b: one WG per (channel d, pass). Each pass convolves the complex pair
// (r0 + i r1). The 8192-pt transform's h=4096 edge stages are fused into
// load (lo: x, hi: x*W_8192^n) and store (y = u + v*conj(W_8192^n)); between
// them each half is an independent 4096-pt FFT-conv: A,B,MID,D,E (5 phases).
// lo-half ends with u[16] kept in REGISTERS (trip E output positions are
// exactly the store positions); hi-half ends with v[16] + combine + store.
// Footprint: LDS 32 KiB, VGPR ~180 -> 2-3 blocks/CU, zero spill (R13 thesis).
__global__ __launch_bounds__(NT)
void fftconv(float* __restrict__ xT, const float2* __restrict__ ThG) {
  __shared__ float2 cb[4096];   // 32 KiB
  const int tid = threadIdx.x;
  const int d = blockIdx.x;
  const int pass = blockIdx.y;

  const int baseB = (tid >> 4) * 256 + (tid & 15);
  const int baseM = tid * 16;
  const float2 ONE = make_float2(1.f, 0.f);

  float sa, ca; __sincosf(-PI_F * (float)tid / 2048.f, &sa, &ca);
  const float2 bA = make_float2(ca, sa);        // W_4096^tid
  const float2 gA = make_float2(ca, -sa);
  float sb, cv; __sincosf(-PI_F * (float)(tid & 15) / 128.f, &sb, &cv);
  const float2 bB = make_float2(cv, sb);        // W_256^(tid&15)
  const float2 gB = make_float2(cv, -sb);
  float sw, cw; __sincosf(-PI_F * (float)tid / 4096.f, &sw, &cw);
  const float2 whi  = make_float2(cw, sw);      // W_8192^tid
  const float2 whic = make_float2(cw, -sw);

  float* r0 = xT + ((size_t)(2 * pass)     * 1024 + d) * 4096;
  float* r1 = xT + ((size_t)(2 * pass + 1) * 1024 + d) * 4096;
  const float2* thl = ThG + (size_t)d * 2 * 4096;
  const float2* thh = thl + 4096;

  float2 u[16];   // lo-half result, pinned through the hi half
  float2 th[16];  // T-hat fragment (transient, prefetched one phase early)

  // ---------------- lo half: input x ----------------
  #pragma unroll
  for (int j = 0; j < 16; ++j) {
    int n = tid + 256 * j;
    cb[P(n)] = make_float2(r0[n], r1[n]);
  }
  __syncthreads();
  tripf(cb, tid, 256, bA);  __syncthreads();
  #pragma unroll
  for (int j = 0; j < 16; ++j) th[j] = thl[tid + 256 * j];  // overlaps trip B
  tripf(cb, baseB, 16, bB); __syncthreads();
  {
    float2 e[16];
    #pragma unroll
    for (int j = 0; j < 16; ++j) e[j] = cb[P(baseM + j)];
    r16_fwd<true>(e, ONE);
    #pragma unroll
    for (int j = 0; j < 16; ++j) e[j] = cmul(e[j], th[j]);
    r16_inv<true>(e, ONE);
    #pragma unroll
    for (int j = 0; j < 16; ++j) cb[P(baseM + j)] = e[j];
  }
  __syncthreads();
  tripi(cb, baseB, 16, gB); __syncthreads();
  #pragma unroll
  for (int j = 0; j < 16; ++j) u[j] = cb[P(tid + 256 * j)];
  r16_inv<false>(u, gA);    // u[m] = lo-half output at n = tid + 256m
  __syncthreads();          // cb reads done; hi half may overwrite

  // ---------------- hi half: input x * W_8192^n ----------------
  #pragma unroll
  for (int j = 0; j < 16; ++j) {
    int n = tid + 256 * j;
    float2 xv = make_float2(r0[n], r1[n]);          // L2-hot re-read
    float2 w = cmul(whi, make_float2(C32x[j], C32y[j]));
    cb[P(n)] = cmul(xv, w);
  }
  __syncthreads();
  tripf(cb, tid, 256, bA);  __syncthreads();
  #pragma unroll
  for (int j = 0; j < 16; ++j) th[j] = thh[tid + 256 * j];
  tripf(cb, baseB, 16, bB); __syncthreads();
  {
    float2 e[16];
    #pragma unroll
    for (int j = 0; j < 16; ++j) e[j] = cb[P(baseM + j)];
    r16_fwd<true>(e, ONE);
    #pragma unroll
    for (int j = 0; j < 16; ++j) e[j] = cmul(e[j], th[j]);
    r16_inv<true>(e, ONE);
    #pragma unroll
    for (int j = 0; j < 16; ++j) cb[P(baseM + j)] = e[j];
  }
  __syncthreads();
  tripi(cb, baseB, 16, gB); __syncthreads();
  {
    float2 v[16];
    #pragma unroll
    for (int j = 0; j < 16; ++j) v[j] = cb[P(tid + 256 * j)];
    r16_inv<false>(v, gA);
    // final h=4096 inverse stage fused into store: y[n] = u + v*conj(W_8192^n)
    #pragma unroll
    for (int m = 0; m < 16; ++m) {
      float2 wc = cmul(whic, make_float2(C32x[m], -C32y[m]));
      float2 t = cmul(v[m], wc);
      int n = tid + 256 * m;
      r0[n] = u[m].x + t.x;
      r1[n] = u[m].y + t.y;
    }
  }
}

// 64x64 tile transpose, 256 threads, float4 global I/O, padded LDS.
// At ~6.6 TB/s measured (R7) — HBM roofline; leave as is.
__global__ __launch_bounds__(256)
void transpose64(const float* __restrict__ src, float* __restrict__ dst, int R, int C) {
  __shared__ float tile[64][65];
  int t  = threadIdx.x;
  int c4 = t & 15;
  int r  = t >> 4;
  size_t slab = (size_t)blockIdx.z * (size_t)R * (size_t)C;
  const float* s = src + slab;
  float* dd = dst + slab;
  int col0 = blockIdx.x * 64, row0 = blockIdx.y * 64;
  #pragma unroll
  for (int k = 0; k < 4; ++k) {
    int rr = r + 16 * k;
    const float4 v = *(const float4*)(s + (size_t)(row0 + rr) * C + col0 + 4 * c4);
    tile[rr][4 * c4 + 0] = v.x;
    tile[rr][4 * c4 + 1] = v.y;
    tile[rr][4 * c4 + 2] = v.z;
    tile[rr][4 * c4 + 3] = v.w;
  }
  __syncthreads();
  #pragma unroll
  for (int k = 0; k < 4; ++k) {
    int cc = r + 16 * k;
    float4 w;
    w.x = tile[4 * c4 + 0][cc];
    w.y = tile[4 * c4 + 1][cc];
    w.z = tile[4 * c4 + 2][cc];
    w.w = tile[4 * c4 + 3][cc];
    *(float4*)(dd + (size_t)(col0 + cc) * R + row0 + 4 * c4) = w;
  }
}

extern "C" void kernel_launch(void* const* d_in, const int* in_sizes, int n_in,
                              void* d_out, int out_size, void* d_ws, size_t ws_size,
                              hipStream_t stream) {
  const float* x = (const float*)d_in[0];   // (4, 4096, 1024)
  const float* t = (const float*)d_in[1];   // (4096, 1024)
  float* out = (float*)d_out;               // (4, 4096, 1024) = 64 MB
  float* ws  = (float*)d_ws;
  float* xT  = ws;                                   // (4, 1024, 4096)  64 MB
  float* tT  = ws + (size_t)4 * 1024 * 4096;         // (1024, 4096)     16 MB
  // T-hat halves live in d_out (2048 * 4096 float2 = 64 MB exactly); consumed
  // by fftconv, then fully overwritten by the final transpose.
  float2* ThG = (float2*)d_out;

  transpose64<<<dim3(16, 64, 4), 256, 0, stream>>>(x, xT, 4096, 1024);
  transpose64<<<dim3(16, 64, 1), 256, 0, stream>>>(t, tT, 4096, 1024);

  that4k<<<dim3(1024, 2), NT, 0, stream>>>(tT, ThG);
  fftconv<<<dim3(1024, 2), NT, 0, stream>>>(xT, ThG);

  transpose64<<<dim3(64, 16, 4), 256, 0, stream>>>(xT, out, 1024, 4096);
}

// Round 14
// 166.702 us; speedup vs baseline: 1.4335x; 1.0502x over previous
//
#include <hip/hip_runtime.h>

#define NT 512
#define SCL (1.0f / 8192.0f)
#define PI_F 3.14159265358979323846f

// XOR swizzle: bijective involution on [0,4096); spreads power-of-2 strided
// trip accesses across banks. Applied at EVERY cb access.
__device__ __forceinline__ int P(int i) { return i ^ ((i >> 5) & 31); }

__device__ __forceinline__ float2 cmul(float2 a, float2 b) {
  return make_float2(a.x * b.x - a.y * b.y, a.x * b.y + a.y * b.x);
}
__device__ __forceinline__ float2 csqr(float2 a) {
  return make_float2(a.x * a.x - a.y * a.y, 2.f * a.x * a.y);
}
__device__ __forceinline__ float2 cadd(float2 a, float2 b) { return make_float2(a.x + b.x, a.y + b.y); }
__device__ __forceinline__ float2 csub(float2 a, float2 b) { return make_float2(a.x - b.x, a.y - b.y); }
__device__ __forceinline__ float2 cmuli (float2 a) { return make_float2(-a.y,  a.x); } // *(+i)
__device__ __forceinline__ float2 cmulmi(float2 a) { return make_float2( a.y, -a.x); } // *(-i)

constexpr float RT2 = 0.70710678118654752440f;
constexpr float CQ1 = 0.92387953251128675613f; // cos(pi/8)
constexpr float SQ1 = 0.38268343236508977173f; // sin(pi/8)
// C8[k] = W8^k = e^{-i pi k/4}
constexpr float C8x[4] = {1.f,  RT2, 0.f, -RT2};
constexpr float C8y[4] = {0.f, -RT2, -1.f, -RT2};
// C16[k] = W16^k = e^{-i pi k/8} (for the W_8192^{512k} rotation chain)
constexpr float C16x1 = CQ1, C16y1 = -SQ1;

// In-register 8-point DIF, stages at register strides 4,2,1 (R7-verified).
// Stage stride s uses twiddle b^{4/s} * W_{2s}^{j mod s}; UNIT means b == 1.
template<bool UNIT>
__device__ __forceinline__ void r8_fwd(float2* e, float2 b) {
  float2 b2, b4;
  if (!UNIT) { b2 = csqr(b); b4 = csqr(b2); }
  #pragma unroll
  for (int j = 0; j < 4; ++j) {
    float2 u = e[j], v = e[j + 4];
    float2 d = csub(u, v);
    e[j] = cadd(u, v);
    float2 c8 = make_float2(C8x[j], C8y[j]);
    if (UNIT) e[j + 4] = (j == 0) ? d : cmul(d, c8);
    else      e[j + 4] = cmul(d, (j == 0) ? b : cmul(b, c8));
  }
  #pragma unroll
  for (int o = 0; o < 8; o += 4) {
    #pragma unroll
    for (int j = 0; j < 2; ++j) {
      float2 u = e[o + j], v = e[o + j + 2];
      float2 d = csub(u, v);
      e[o + j] = cadd(u, v);
      if (UNIT) e[o + j + 2] = (j == 0) ? d : cmulmi(d);
      else      e[o + j + 2] = cmul(d, (j == 0) ? b2 : cmulmi(b2));
    }
  }
  #pragma unroll
  for (int o = 0; o < 8; o += 2) {
    float2 u = e[o], v = e[o + 1];
    float2 d = csub(u, v);
    e[o] = cadd(u, v);
    e[o + 1] = UNIT ? d : cmul(d, b4);
  }
}

// In-register 8-point DIT inverse, stages at strides 1,2,4. g = conj(beta).
template<bool UNIT>
__device__ __forceinline__ void r8_inv(float2* e, float2 g) {
  float2 g2, g4;
  if (!UNIT) { g2 = csqr(g); g4 = csqr(g2); }
  #pragma unroll
  for (int o = 0; o < 8; o += 2) {
    float2 t = UNIT ? e[o + 1] : cmul(e[o + 1], g4);
    float2 u = e[o];
    e[o] = cadd(u, t); e[o + 1] = csub(u, t);
  }
  #pragma unroll
  for (int o = 0; o < 8; o += 4) {
    #pragma unroll
    for (int j = 0; j < 2; ++j) {
      float2 v = e[o + j + 2];
      float2 t;
      if (UNIT) t = (j == 0) ? v : cmuli(v);
      else      t = cmul(v, (j == 0) ? g2 : cmuli(g2));
      float2 u = e[o + j];
      e[o + j] = cadd(u, t); e[o + j + 2] = csub(u, t);
    }
  }
  #pragma unroll
  for (int j = 0; j < 4; ++j) {
    float2 v = e[j + 4];
    float2 t;
    float2 c8c = make_float2(C8x[j], -C8y[j]);
    if (UNIT) t = (j == 0) ? v : cmul(v, c8c);
    else      t = cmul(v, (j == 0) ? g : cmul(g, c8c));
    float2 u = e[j];
    e[j] = cadd(u, t); e[j + 4] = csub(u, t);
  }
}

// Single-group radix-8 trips on the 4096-entry buffer (one group per thread).
__device__ __forceinline__ void t8f(float2* cb, int base, int G, float2 b) {
  float2 e[8];
  #pragma unroll
  for (int j = 0; j < 8; ++j) e[j] = cb[P(base + G * j)];
  r8_fwd<false>(e, b);
  #pragma unroll
  for (int j = 0; j < 8; ++j) cb[P(base + G * j)] = e[j];
}

__device__ __forceinline__ void t8i(float2* cb, int base, int G, float2 g) {
  float2 e[8];
  #pragma unroll
  for (int j = 0; j < 8; ++j) e[j] = cb[P(base + G * j)];
  r8_inv<false>(e, g);
  #pragma unroll
  for (int j = 0; j < 8; ++j) cb[P(base + G * j)] = e[j];
}

// K2a: T-hat halves via the SAME radix-8 pipeline as fftconv (shared digit-
// reversal ordering). half0 input = t[n]; half1 = t[n]*W_8192^n. 4096 = 8^4:
// trips A(G=512), B(G=64), C(G=8), MID-fwd(G=1). Scaled output written
// consumption-ordered: ThG[(2d+half)*4096 + tid + 512*j].
__global__ __launch_bounds__(NT)
void that8h(const float* __restrict__ tT, float2* __restrict__ ThG) {
  __shared__ float2 cb[4096];   // 32 KiB
  const int tid = threadIdx.x;
  const int d = blockIdx.x;
  const int half = blockIdx.y;

  const int baseB = ((tid >> 6) << 9) + (tid & 63);
  const int baseC = ((tid >> 3) << 6) + (tid & 7);

  float s0, c0; __sincosf(-PI_F * (float)tid / 2048.f, &s0, &c0);
  const float2 bA = make_float2(c0, s0);            // W_4096^tid
  float s1, c1; __sincosf(-PI_F * (float)(tid & 63) / 256.f, &s1, &c1);
  const float2 bB = make_float2(c1, s1);            // W_512^(tid&63)
  float s2, c2; __sincosf(-PI_F * (float)(tid & 7) / 32.f, &s2, &c2);
  const float2 bC = make_float2(c2, s2);            // W_64^(tid&7)
  float sw, cw; __sincosf(-PI_F * (float)tid / 4096.f, &sw, &cw);
  const float2 whi = make_float2(cw, sw);           // W_8192^tid
  const float2 ROT = make_float2(C16x1, C16y1);     // e^{-i pi/8} = W_8192^512

  const float* tp = tT + (size_t)d * 4096;
  {
    float2 w = whi;
    #pragma unroll
    for (int k = 0; k < 8; ++k) {
      int n = tid + NT * k;
      float tv = tp[n];
      float2 v;
      if (half == 0) v = make_float2(tv, 0.f);
      else           v = make_float2(tv * w.x, tv * w.y);
      cb[P(n)] = v;
      w = cmul(w, ROT);
    }
  }
  __syncthreads();
  t8f(cb, tid, 512, bA);   __syncthreads();
  t8f(cb, baseB, 64, bB);  __syncthreads();
  t8f(cb, baseC, 8, bC);   __syncthreads();
  float2* thg = ThG + ((size_t)d * 2 + half) * 4096;
  float2 e[8];
  #pragma unroll
  for (int j = 0; j < 8; ++j) e[j] = cb[P(tid * 8 + j)];
  r8_fwd<true>(e, make_float2(1.f, 0.f));
  #pragma unroll
  for (int j = 0; j < 8; ++j)
    thg[tid + 512 * j] = make_float2(e[j].x * SCL, e[j].y * SCL);
}

// K2b: one WG per (channel d, pass). Half-split 8192-pt conv (R13 structure)
// rebuilt at NT=512 / radix-8 for the max-occupancy geometry: the NT=512 hard
// 128-VGPR cap fits radix-8 state (e[8]+th[8]+u[8]+misc ~90 live, R7 precedent)
// -> 4 waves/SIMD, and 32 KiB LDS -> 2 blocks/CU (16 waves/CU; R13 had 12).
// Per half: load(-fused h=4096 modulation), A(G=512), B(G=64), C(G=8),
// MID(unit fwd + That* + unit inv), C', B', A'(in regs). lo keeps u[8] in
// registers; hi combines y = u + v*conj(W_8192^n) fused into the store.
__global__ __launch_bounds__(NT)
void fftconv(float* __restrict__ xT, const float2* __restrict__ ThG) {
  __shared__ float2 cb[4096];   // 32 KiB
  const int tid = threadIdx.x;
  const int d = blockIdx.x;
  const int pass = blockIdx.y;

  const int baseB = ((tid >> 6) << 9) + (tid & 63);
  const int baseC = ((tid >> 3) << 6) + (tid & 7);
  const int baseM = tid << 3;
  const float2 ONE = make_float2(1.f, 0.f);

  float s0, c0; __sincosf(-PI_F * (float)tid / 2048.f, &s0, &c0);
  const float2 bA = make_float2(c0, s0);            // W_4096^tid
  const float2 gA = make_float2(c0, -s0);
  float s1, c1; __sincosf(-PI_F * (float)(tid & 63) / 256.f, &s1, &c1);
  const float2 bB = make_float2(c1, s1);            // W_512^(tid&63)
  const float2 gB = make_float2(c1, -s1);
  float s2, c2; __sincosf(-PI_F * (float)(tid & 7) / 32.f, &s2, &c2);
  const float2 bC = make_float2(c2, s2);            // W_64^(tid&7)
  const float2 gC = make_float2(c2, -s2);
  float sw, cw; __sincosf(-PI_F * (float)tid / 4096.f, &sw, &cw);
  const float2 whi  = make_float2(cw, sw);          // W_8192^tid
  const float2 whic = make_float2(cw, -sw);
  const float2 ROT  = make_float2(C16x1, C16y1);    // e^{-i pi/8}
  const float2 ROTc = make_float2(C16x1, -C16y1);   // e^{+i pi/8}

  float* r0 = xT + ((size_t)(2 * pass)     * 1024 + d) * 4096;
  float* r1 = xT + ((size_t)(2 * pass + 1) * 1024 + d) * 4096;
  const float2* thl = ThG + (size_t)d * 2 * 4096;
  const float2* thh = thl + 4096;

  float2 u[8];    // lo-half result, pinned through the hi half (16 VGPRs)
  float2 th[8];   // T-hat fragment (prefetched one phase early)

  // ---------------- lo half: input x ----------------
  #pragma unroll
  for (int k = 0; k < 8; ++k) {
    int n = tid + NT * k;
    cb[P(n)] = make_float2(r0[n], r1[n]);
  }
  __syncthreads();
  t8f(cb, tid, 512, bA);   __syncthreads();
  t8f(cb, baseB, 64, bB);  __syncthreads();
  #pragma unroll
  for (int j = 0; j < 8; ++j) th[j] = thl[tid + 512 * j];  // overlaps trip C
  t8f(cb, baseC, 8, bC);   __syncthreads();
  {
    float2 e[8];
    #pragma unroll
    for (int j = 0; j < 8; ++j) e[j] = cb[P(baseM + j)];
    r8_fwd<true>(e, ONE);
    #pragma unroll
    for (int j = 0; j < 8; ++j) e[j] = cmul(e[j], th[j]);
    r8_inv<true>(e, ONE);
    #pragma unroll
    for (int j = 0; j < 8; ++j) cb[P(baseM + j)] = e[j];
  }
  __syncthreads();
  t8i(cb, baseC, 8, gC);   __syncthreads();
  t8i(cb, baseB, 64, gB);  __syncthreads();
  #pragma unroll
  for (int j = 0; j < 8; ++j) u[j] = cb[P(tid + 512 * j)];
  r8_inv<false>(u, gA);     // u[k] = lo-half output at n = tid + 512k
  __syncthreads();          // cb reads done; hi half may overwrite

  // ---------------- hi half: input x * W_8192^n ----------------
  {
    float2 w = whi;
    #pragma unroll
    for (int k = 0; k < 8; ++k) {
      int n = tid + NT * k;
      float2 xv = make_float2(r0[n], r1[n]);        // L2-hot re-read
      cb[P(n)] = cmul(xv, w);
      w = cmul(w, ROT);
    }
  }
  __syncthreads();
  t8f(cb, tid, 512, bA);   __syncthreads();
  t8f(cb, baseB, 64, bB);  __syncthreads();
  #pragma unroll
  for (int j = 0; j < 8; ++j) th[j] = thh[tid + 512 * j];
  t8f(cb, baseC, 8, bC);   __syncthreads();
  {
    float2 e[8];
    #pragma unroll
    for (int j = 0; j < 8; ++j) e[j] = cb[P(baseM + j)];
    r8_fwd<true>(e, ONE);
    #pragma unroll
    for (int j = 0; j < 8; ++j) e[j] = cmul(e[j], th[j]);
    r8_inv<true>(e, ONE);
    #pragma unroll
    for (int j = 0; j < 8; ++j) cb[P(baseM + j)] = e[j];
  }
  __syncthreads();
  t8i(cb, baseC, 8, gC);   __syncthreads();
  t8i(cb, baseB, 64, gB);  __syncthreads();
  {
    float2 v[8];
    #pragma unroll
    for (int j = 0; j < 8; ++j) v[j] = cb[P(tid + 512 * j)];
    r8_inv<false>(v, gA);
    // final h=4096 inverse stage fused into the store: y = u + v*conj(W_8192^n)
    float2 wc = whic;
    #pragma unroll
    for (int k = 0; k < 8; ++k) {
      float2 t = cmul(v[k], wc);
      int n = tid + NT * k;
      r0[n] = u[k].x + t.x;
      r1[n] = u[k].y + t.y;
      wc = cmul(wc, ROTc);
    }
  }
}

// 64x64 tile transpose, 256 threads, float4 global I/O, padded LDS.
// At ~6.6 TB/s measured (R7) — HBM roofline; leave as is.
__global__ __launch_bounds__(256)
void transpose64(const float* __restrict__ src, float* __restrict__ dst, int R, int C) {
  __shared__ float tile[64][65];
  int t  = threadIdx.x;
  int c4 = t & 15;
  int r  = t >> 4;
  size_t slab = (size_t)blockIdx.z * (size_t)R * (size_t)C;
  const float* s = src + slab;
  float* dd = dst + slab;
  int col0 = blockIdx.x * 64, row0 = blockIdx.y * 64;
  #pragma unroll
  for (int k = 0; k < 4; ++k) {
    int rr = r + 16 * k;
    const float4 v = *(const float4*)(s + (size_t)(row0 + rr) * C + col0 + 4 * c4);
    tile[rr][4 * c4 + 0] = v.x;
    tile[rr][4 * c4 + 1] = v.y;
    tile[rr][4 * c4 + 2] = v.z;
    tile[rr][4 * c4 + 3] = v.w;
  }
  __syncthreads();
  #pragma unroll
  for (int k = 0; k < 4; ++k) {
    int cc = r + 16 * k;
    float4 w;
    w.x = tile[4 * c4 + 0][cc];
    w.y = tile[4 * c4 + 1][cc];
    w.z = tile[4 * c4 + 2][cc];
    w.w = tile[4 * c4 + 3][cc];
    *(float4*)(dd + (size_t)(col0 + cc) * R + row0 + 4 * c4) = w;
  }
}

extern "C" void kernel_launch(void* const* d_in, const int* in_sizes, int n_in,
                              void* d_out, int out_size, void* d_ws, size_t ws_size,
                              hipStream_t stream) {
  const float* x = (const float*)d_in[0];   // (4, 4096, 1024)
  const float* t = (const float*)d_in[1];   // (4096, 1024)
  float* out = (float*)d_out;               // (4, 4096, 1024) = 64 MB
  float* ws  = (float*)d_ws;
  float* xT  = ws;                                   // (4, 1024, 4096)  64 MB
  float* tT  = ws + (size_t)4 * 1024 * 4096;         // (1024, 4096)     16 MB
  // T-hat halves live in d_out (2048 * 4096 float2 = 64 MB exactly); consumed
  // by fftconv, then fully overwritten by the final transpose.
  float2* ThG = (float2*)d_out;

  transpose64<<<dim3(16, 64, 4), 256, 0, stream>>>(x, xT, 4096, 1024);
  transpose64<<<dim3(16, 64, 1), 256, 0, stream>>>(t, tT, 4096, 1024);

  that8h<<<dim3(1024, 2), NT, 0, stream>>>(tT, ThG);
  fftconv<<<dim3(1024, 2), NT, 0, stream>>>(xT, ThG);

  transpose64<<<dim3(64, 16, 4), 256, 0, stream>>>(xT, out, 1024, 4096);
}

// Round 15
// 153.819 us; speedup vs baseline: 1.5535x; 1.0838x over previous
//
#include <hip/hip_runtime.h>

#define NT 512
#define SCL (1.0f / 8192.0f)
#define PI_F 3.14159265358979323846f

// XOR swizzle: bijective involution on [0,4096); spreads power-of-2 strided
// trip accesses across banks. Applied at EVERY cb access.
__device__ __forceinline__ int P(int i) { return i ^ ((i >> 5) & 31); }

__device__ __forceinline__ float2 cmul(float2 a, float2 b) {
  return make_float2(a.x * b.x - a.y * b.y, a.x * b.y + a.y * b.x);
}
__device__ __forceinline__ float2 csqr(float2 a) {
  return make_float2(a.x * a.x - a.y * a.y, 2.f * a.x * a.y);
}
__device__ __forceinline__ float2 cadd(float2 a, float2 b) { return make_float2(a.x + b.x, a.y + b.y); }
__device__ __forceinline__ float2 csub(float2 a, float2 b) { return make_float2(a.x - b.x, a.y - b.y); }
__device__ __forceinline__ float2 cmuli (float2 a) { return make_float2(-a.y,  a.x); } // *(+i)
__device__ __forceinline__ float2 cmulmi(float2 a) { return make_float2( a.y, -a.x); } // *(-i)

constexpr float RT2 = 0.70710678118654752440f;
constexpr float CQ1 = 0.92387953251128675613f; // cos(pi/8)
constexpr float SQ1 = 0.38268343236508977173f; // sin(pi/8)
// C8[k] = W8^k = e^{-i pi k/4}
constexpr float C8x[4] = {1.f,  RT2, 0.f, -RT2};
constexpr float C8y[4] = {0.f, -RT2, -1.f, -RT2};
// C16[k] = W16^k = e^{-i pi k/8} — used as W_8192^{512k} in the fused loads
constexpr float C16x[8] = {1.f,  CQ1,  RT2,  SQ1, 0.f, -SQ1, -RT2, -CQ1};
constexpr float C16y[8] = {0.f, -SQ1, -RT2, -CQ1, -1.f, -CQ1, -RT2, -SQ1};

// In-register 8-point DIF, stages at register strides 4,2,1 (R7/R14-verified).
// Stage stride s uses twiddle b^{4/s} * W_{2s}^{j mod s}; UNIT means b == 1.
template<bool UNIT>
__device__ __forceinline__ void r8_fwd(float2* e, float2 b) {
  float2 b2, b4;
  if (!UNIT) { b2 = csqr(b); b4 = csqr(b2); }
  #pragma unroll
  for (int j = 0; j < 4; ++j) {
    float2 u = e[j], v = e[j + 4];
    float2 d = csub(u, v);
    e[j] = cadd(u, v);
    float2 c8 = make_float2(C8x[j], C8y[j]);
    if (UNIT) e[j + 4] = (j == 0) ? d : cmul(d, c8);
    else      e[j + 4] = cmul(d, (j == 0) ? b : cmul(b, c8));
  }
  #pragma unroll
  for (int o = 0; o < 8; o += 4) {
    #pragma unroll
    for (int j = 0; j < 2; ++j) {
      float2 u = e[o + j], v = e[o + j + 2];
      float2 d = csub(u, v);
      e[o + j] = cadd(u, v);
      if (UNIT) e[o + j + 2] = (j == 0) ? d : cmulmi(d);
      else      e[o + j + 2] = cmul(d, (j == 0) ? b2 : cmulmi(b2));
    }
  }
  #pragma unroll
  for (int o = 0; o < 8; o += 2) {
    float2 u = e[o], v = e[o + 1];
    float2 d = csub(u, v);
    e[o] = cadd(u, v);
    e[o + 1] = UNIT ? d : cmul(d, b4);
  }
}

// In-register 8-point DIT inverse, stages at strides 1,2,4. g = conj(beta).
template<bool UNIT>
__device__ __forceinline__ void r8_inv(float2* e, float2 g) {
  float2 g2, g4;
  if (!UNIT) { g2 = csqr(g); g4 = csqr(g2); }
  #pragma unroll
  for (int o = 0; o < 8; o += 2) {
    float2 t = UNIT ? e[o + 1] : cmul(e[o + 1], g4);
    float2 u = e[o];
    e[o] = cadd(u, t); e[o + 1] = csub(u, t);
  }
  #pragma unroll
  for (int o = 0; o < 8; o += 4) {
    #pragma unroll
    for (int j = 0; j < 2; ++j) {
      float2 v = e[o + j + 2];
      float2 t;
      if (UNIT) t = (j == 0) ? v : cmuli(v);
      else      t = cmul(v, (j == 0) ? g2 : cmuli(g2));
      float2 u = e[o + j];
      e[o + j] = cadd(u, t); e[o + j + 2] = csub(u, t);
    }
  }
  #pragma unroll
  for (int j = 0; j < 4; ++j) {
    float2 v = e[j + 4];
    float2 t;
    float2 c8c = make_float2(C8x[j], -C8y[j]);
    if (UNIT) t = (j == 0) ? v : cmul(v, c8c);
    else      t = cmul(v, (j == 0) ? g : cmul(g, c8c));
    float2 u = e[j];
    e[j] = cadd(u, t); e[j + 4] = csub(u, t);
  }
}

// Single-group radix-8 trips on the 4096-entry buffer (one group per thread).
__device__ __forceinline__ void t8f(float2* cb, int base, int G, float2 b) {
  float2 e[8];
  #pragma unroll
  for (int j = 0; j < 8; ++j) e[j] = cb[P(base + G * j)];
  r8_fwd<false>(e, b);
  #pragma unroll
  for (int j = 0; j < 8; ++j) cb[P(base + G * j)] = e[j];
}

__device__ __forceinline__ void t8i(float2* cb, int base, int G, float2 g) {
  float2 e[8];
  #pragma unroll
  for (int j = 0; j < 8; ++j) e[j] = cb[P(base + G * j)];
  r8_inv<false>(e, g);
  #pragma unroll
  for (int j = 0; j < 8; ++j) cb[P(base + G * j)] = e[j];
}

// K2a: T-hat halves via the SAME radix-8 pipeline as fftconv (shared digit-
// reversal ordering). half0 input = t[n]; half1 = t[n]*W_8192^n. 4096 = 8^4.
// R15: the standalone load phase is FUSED into trip A — trip A's element set
// (n = tid + 512j) equals the load set, so load straight into e[8], r8_fwd,
// write cb once (saves one LDS round trip + barrier).
// Scaled output written consumption-ordered: ThG[(2d+half)*4096 + tid + 512*j].
__global__ __launch_bounds__(NT)
void that8h(const float* __restrict__ tT, float2* __restrict__ ThG) {
  __shared__ float2 cb[4096];   // 32 KiB
  const int tid = threadIdx.x;
  const int d = blockIdx.x;
  const int half = blockIdx.y;

  const int baseB = ((tid >> 6) << 9) + (tid & 63);
  const int baseC = ((tid >> 3) << 6) + (tid & 7);

  float s0, c0; __sincosf(-PI_F * (float)tid / 2048.f, &s0, &c0);
  const float2 bA = make_float2(c0, s0);            // W_4096^tid
  float s1, c1; __sincosf(-PI_F * (float)(tid & 63) / 256.f, &s1, &c1);
  const float2 bB = make_float2(c1, s1);            // W_512^(tid&63)
  float s2, c2; __sincosf(-PI_F * (float)(tid & 7) / 32.f, &s2, &c2);
  const float2 bC = make_float2(c2, s2);            // W_64^(tid&7)
  float sw, cw; __sincosf(-PI_F * (float)tid / 4096.f, &sw, &cw);
  const float2 whi = make_float2(cw, sw);           // W_8192^tid

  const float* tp = tT + (size_t)d * 4096;
  {
    float2 e[8];
    #pragma unroll
    for (int j = 0; j < 8; ++j) {
      int n = tid + 512 * j;
      float tv = tp[n];
      if (half == 0) e[j] = make_float2(tv, 0.f);
      else {
        float2 w = (j == 0) ? whi : cmul(whi, make_float2(C16x[j], C16y[j])); // W_8192^n
        e[j] = make_float2(tv * w.x, tv * w.y);
      }
    }
    r8_fwd<false>(e, bA);
    #pragma unroll
    for (int j = 0; j < 8; ++j) cb[P(tid + 512 * j)] = e[j];
  }
  __syncthreads();
  t8f(cb, baseB, 64, bB);  __syncthreads();
  t8f(cb, baseC, 8, bC);   __syncthreads();
  float2* thg = ThG + ((size_t)d * 2 + half) * 4096;
  float2 e[8];
  #pragma unroll
  for (int j = 0; j < 8; ++j) e[j] = cb[P(tid * 8 + j)];
  r8_fwd<true>(e, make_float2(1.f, 0.f));
  #pragma unroll
  for (int j = 0; j < 8; ++j)
    thg[tid + 512 * j] = make_float2(e[j].x * SCL, e[j].y * SCL);
}

// K2b: one WG per (channel d, pass). Half-split 8192-pt conv (R13/R14
// structure) at the max-occupancy geometry (NT=512, radix-8, 112 VGPR,
// 32 KiB LDS -> 2 blocks/CU, 16 waves/CU). R15 change: global load fused
// into trip A on BOTH halves (same element set) — one fewer LDS round trip
// and barrier per half; hi-half modulation becomes per-j constants
// whi*C16[j] instead of a serial rotation chain.
// Per half: A(fused load), B(G=64), C(G=8), MID(unit fwd + That* + unit inv),
// C', B', A'(in regs; lo keeps u[8], hi combines y = u + v*conj(W_8192^n)
// fused into the store).
__global__ __launch_bounds__(NT)
void fftconv(float* __restrict__ xT, const float2* __restrict__ ThG) {
  __shared__ float2 cb[4096];   // 32 KiB
  const int tid = threadIdx.x;
  const int d = blockIdx.x;
  const int pass = blockIdx.y;

  const int baseB = ((tid >> 6) << 9) + (tid & 63);
  const int baseC = ((tid >> 3) << 6) + (tid & 7);
  const int baseM = tid << 3;
  const float2 ONE = make_float2(1.f, 0.f);

  float s0, c0; __sincosf(-PI_F * (float)tid / 2048.f, &s0, &c0);
  const float2 bA = make_float2(c0, s0);            // W_4096^tid
  const float2 gA = make_float2(c0, -s0);
  float s1, c1; __sincosf(-PI_F * (float)(tid & 63) / 256.f, &s1, &c1);
  const float2 bB = make_float2(c1, s1);            // W_512^(tid&63)
  const float2 gB = make_float2(c1, -s1);
  float s2, c2; __sincosf(-PI_F * (float)(tid & 7) / 32.f, &s2, &c2);
  const float2 bC = make_float2(c2, s2);            // W_64^(tid&7)
  const float2 gC = make_float2(c2, -s2);
  float sw, cw; __sincosf(-PI_F * (float)tid / 4096.f, &sw, &cw);
  const float2 whi  = make_float2(cw, sw);          // W_8192^tid
  const float2 whic = make_float2(cw, -sw);

  float* r0 = xT + ((size_t)(2 * pass)     * 1024 + d) * 4096;
  float* r1 = xT + ((size_t)(2 * pass + 1) * 1024 + d) * 4096;
  const float2* thl = ThG + (size_t)d * 2 * 4096;
  const float2* thh = thl + 4096;

  float2 u[8];    // lo-half result, pinned through the hi half (16 VGPRs)
  float2 th[8];   // T-hat fragment (prefetched one phase early)

  // ---------------- lo half: input x (load fused into trip A) ----------------
  {
    float2 e[8];
    #pragma unroll
    for (int j = 0; j < 8; ++j) {
      int n = tid + 512 * j;
      e[j] = make_float2(r0[n], r1[n]);
    }
    r8_fwd<false>(e, bA);
    #pragma unroll
    for (int j = 0; j < 8; ++j) cb[P(tid + 512 * j)] = e[j];
  }
  __syncthreads();
  t8f(cb, baseB, 64, bB);  __syncthreads();
  #pragma unroll
  for (int j = 0; j < 8; ++j) th[j] = thl[tid + 512 * j];  // overlaps trip C
  t8f(cb, baseC, 8, bC);   __syncthreads();
  {
    float2 e[8];
    #pragma unroll
    for (int j = 0; j < 8; ++j) e[j] = cb[P(baseM + j)];
    r8_fwd<true>(e, ONE);
    #pragma unroll
    for (int j = 0; j < 8; ++j) e[j] = cmul(e[j], th[j]);
    r8_inv<true>(e, ONE);
    #pragma unroll
    for (int j = 0; j < 8; ++j) cb[P(baseM + j)] = e[j];
  }
  __syncthreads();
  t8i(cb, baseC, 8, gC);   __syncthreads();
  t8i(cb, baseB, 64, gB);  __syncthreads();
  #pragma unroll
  for (int j = 0; j < 8; ++j) u[j] = cb[P(tid + 512 * j)];
  r8_inv<false>(u, gA);     // u[k] = lo-half output at n = tid + 512k
  __syncthreads();          // cb reads done; hi half may overwrite

  // ------------- hi half: input x * W_8192^n (load fused into trip A) -------------
  {
    float2 e[8];
    #pragma unroll
    for (int j = 0; j < 8; ++j) {
      int n = tid + 512 * j;
      float2 xv = make_float2(r0[n], r1[n]);        // L2-hot re-read
      float2 w = (j == 0) ? whi : cmul(whi, make_float2(C16x[j], C16y[j])); // W_8192^n
      e[j] = cmul(xv, w);
    }
    r8_fwd<false>(e, bA);
    #pragma unroll
    for (int j = 0; j < 8; ++j) cb[P(tid + 512 * j)] = e[j];
  }
  __syncthreads();
  t8f(cb, baseB, 64, bB);  __syncthreads();
  #pragma unroll
  for (int j = 0; j < 8; ++j) th[j] = thh[tid + 512 * j];
  t8f(cb, baseC, 8, bC);   __syncthreads();
  {
    float2 e[8];
    #pragma unroll
    for (int j = 0; j < 8; ++j) e[j] = cb[P(baseM + j)];
    r8_fwd<true>(e, ONE);
    #pragma unroll
    for (int j = 0; j < 8; ++j) e[j] = cmul(e[j], th[j]);
    r8_inv<true>(e, ONE);
    #pragma unroll
    for (int j = 0; j < 8; ++j) cb[P(baseM + j)] = e[j];
  }
  __syncthreads();
  t8i(cb, baseC, 8, gC);   __syncthreads();
  t8i(cb, baseB, 64, gB);  __syncthreads();
  {
    float2 v[8];
    #pragma unroll
    for (int j = 0; j < 8; ++j) v[j] = cb[P(tid + 512 * j)];
    r8_inv<false>(v, gA);
    // final h=4096 inverse stage fused into the store: y = u + v*conj(W_8192^n)
    #pragma unroll
    for (int k = 0; k < 8; ++k) {
      float2 wc = (k == 0) ? whic : cmul(whic, make_float2(C16x[k], -C16y[k]));
      float2 t = cmul(v[k], wc);
      int n = tid + 512 * k;
      r0[n] = u[k].x + t.x;
      r1[n] = u[k].y + t.y;
    }
  }
}

// 64x64 tile transpose, 256 threads, float4 global I/O, padded LDS.
// At ~6.6 TB/s measured (R7) — HBM roofline; leave as is.
__global__ __launch_bounds__(256)
void transpose64(const float* __restrict__ src, float* __restrict__ dst, int R, int C) {
  __shared__ float tile[64][65];
  int t  = threadIdx.x;
  int c4 = t & 15;
  int r  = t >> 4;
  size_t slab = (size_t)blockIdx.z * (size_t)R * (size_t)C;
  const float* s = src + slab;
  float* dd = dst + slab;
  int col0 = blockIdx.x * 64, row0 = blockIdx.y * 64;
  #pragma unroll
  for (int k = 0; k < 4; ++k) {
    int rr = r + 16 * k;
    const float4 v = *(const float4*)(s + (size_t)(row0 + rr) * C + col0 + 4 * c4);
    tile[rr][4 * c4 + 0] = v.x;
    tile[rr][4 * c4 + 1] = v.y;
    tile[rr][4 * c4 + 2] = v.z;
    tile[rr][4 * c4 + 3] = v.w;
  }
  __syncthreads();
  #pragma unroll
  for (int k = 0; k < 4; ++k) {
    int cc = r + 16 * k;
    float4 w;
    w.x = tile[4 * c4 + 0][cc];
    w.y = tile[4 * c4 + 1][cc];
    w.z = tile[4 * c4 + 2][cc];
    w.w = tile[4 * c4 + 3][cc];
    *(float4*)(dd + (size_t)(col0 + cc) * R + row0 + 4 * c4) = w;
  }
}

extern "C" void kernel_launch(void* const* d_in, const int* in_sizes, int n_in,
                              void* d_out, int out_size, void* d_ws, size_t ws_size,
                              hipStream_t stream) {
  const float* x = (const float*)d_in[0];   // (4, 4096, 1024)
  const float* t = (const float*)d_in[1];   // (4096, 1024)
  float* out = (float*)d_out;               // (4, 4096, 1024) = 64 MB
  float* ws  = (float*)d_ws;
  float* xT  = ws;                                   // (4, 1024, 4096)  64 MB
  float* tT  = ws + (size_t)4 * 1024 * 4096;         // (1024, 4096)     16 MB
  // T-hat halves live in d_out (2048 * 4096 float2 = 64 MB exactly); consumed
  // by fftconv, then fully overwritten by the final transpose.
  float2* ThG = (float2*)d_out;

  transpose64<<<dim3(16, 64, 4), 256, 0, stream>>>(x, xT, 4096, 1024);
  transpose64<<<dim3(16, 64, 1), 256, 0, stream>>>(t, tT, 4096, 1024);

  that8h<<<dim3(1024, 2), NT, 0, stream>>>(tT, ThG);
  fftconv<<<dim3(1024, 2), NT, 0, stream>>>(xT, ThG);

  transpose64<<<dim3(64, 16, 4), 256, 0, stream>>>(xT, out, 1024, 4096);
}